// Round 8
// baseline (1796.336 us; speedup 1.0000x reference)
//
#include <hip/hip_runtime.h>
#include <hip/hip_bf16.h>
#include <math.h>

typedef unsigned short u16;
typedef unsigned int u32;
typedef __bf16 bf16x8 __attribute__((ext_vector_type(8)));
typedef float f32x4 __attribute__((ext_vector_type(4)));

#define MROWS 100352   // 32 * 56 * 56
#define CDIM 512
#define SCALE_ATTN 0.17677669529663687f

__device__ __forceinline__ u16 f2bf(float f) {
    u32 u = __float_as_uint(f);
    u32 r = (u + 0x7fffu + ((u >> 16) & 1u)) >> 16;   // RNE
    return (u16)r;
}
__device__ __forceinline__ float bf2f(u16 h) {
    return __uint_as_float(((u32)h) << 16);
}

// ---------------- transpose + cast: fp32 W[K][N] -> bf16 WT[N][K] ----------------
__global__ void transpose_cast(const float* __restrict__ W, u16* __restrict__ WT, int K, int N) {
    int idx = blockIdx.x * 256 + threadIdx.x;
    if (idx >= K * N) return;
    int k = idx / N, n = idx % N;
    WT[(size_t)n * K + k] = f2bf(W[idx]);
}

// ---------------- LayerNorm fp32 -> bf16, one wave per row (C=512) ----------------
__global__ __launch_bounds__(256) void ln_kernel(const float* __restrict__ x, const float* __restrict__ g,
                                                 const float* __restrict__ bta, u16* __restrict__ out) {
    int row = blockIdx.x * 4 + (threadIdx.x >> 6);
    int lane = threadIdx.x & 63;
    const float* xr = x + (size_t)row * CDIM + lane * 8;
    float4 v0 = *(const float4*)xr;
    float4 v1 = *(const float4*)(xr + 4);
    float xv[8] = {v0.x, v0.y, v0.z, v0.w, v1.x, v1.y, v1.z, v1.w};
    float s = 0.f, ss = 0.f;
#pragma unroll
    for (int i = 0; i < 8; ++i) { s += xv[i]; ss += xv[i] * xv[i]; }
#pragma unroll
    for (int o = 1; o < 64; o <<= 1) { s += __shfl_xor(s, o); ss += __shfl_xor(ss, o); }
    float mu = s * (1.f / CDIM);
    float var = ss * (1.f / CDIM) - mu * mu;
    float rs = rsqrtf(var + 1e-6f);
    int c = lane * 8;
    u32 pk[4];
#pragma unroll
    for (int i = 0; i < 4; ++i) {
        float y0 = (xv[2 * i] - mu) * rs * g[c + 2 * i] + bta[c + 2 * i];
        float y1 = (xv[2 * i + 1] - mu) * rs * g[c + 2 * i + 1] + bta[c + 2 * i + 1];
        pk[i] = (u32)f2bf(y0) | ((u32)f2bf(y1) << 16);
    }
    uint4 ov; ov.x = pk[0]; ov.y = pk[1]; ov.z = pk[2]; ov.w = pk[3];
    *(uint4*)(out + (size_t)row * CDIM + c) = ov;
}

// ---------------- bf16 GEMM: C[M,N] = A[M,K] * BT[N,K]^T ----------------
// 128x128 tile, BK=64, 4 waves (2x2), 2-buffer 64KB LDS -> 2 blocks/CU.
// Counted-vmcnt pipeline, 2-tile prefetch distance via issue-after-close.
#define BM 128
#define BN 128
#define BK 64
#define BUFE (BM * BK + BN * BK)   // 16384 u16 = 32KB per buffer

enum { EPI_BF16 = 0, EPI_GELU_BF16 = 1, EPI_RES_F32 = 2 };

__device__ __forceinline__ void gload_lds16(const void* g, void* l) {
    __builtin_amdgcn_global_load_lds(
        (const __attribute__((address_space(1))) u32*)g,
        (__attribute__((address_space(3))) u32*)l, 16, 0, 0);
}

#define WAITVM8() asm volatile("s_waitcnt vmcnt(8)" ::: "memory")
#define WAITVM0() asm volatile("s_waitcnt vmcnt(0)" ::: "memory")
#define BARRIER() __builtin_amdgcn_s_barrier()
#define SCHEDBAR() __builtin_amdgcn_sched_barrier(0)

__device__ __forceinline__ float gelu_tanh(float x) {
    float y = 0.7978845608028654f * (x + 0.044715f * x * x * x);
    y = fmaxf(y, -20.f);
    float u = __expf(-2.f * y);
    float th = (1.f - u) / (1.f + u);
    return 0.5f * x * (1.f + th);
}

template <int EPI>
__global__ __launch_bounds__(256, 2) void gemm_bt(const u16* __restrict__ A, const u16* __restrict__ BT,
                                                  const float* __restrict__ bias, const float* __restrict__ res,
                                                  void* __restrict__ outp, int M, int N, int K, int nnb) {
    __shared__ __align__(16) u16 smem[2 * BUFE];   // 64 KB

    const int t = threadIdx.x;
    const int lane = t & 63;
    const int w = t >> 6;
    const int wr = w >> 1, wc = w & 1;

    const int nwg = gridDim.x;
    const int chunk = nwg >> 3;
    const int wg = (blockIdx.x & 7) * chunk + (blockIdx.x >> 3);
    const int m0 = (wg / nnb) * BM;
    const int n0 = (wg % nnb) * BN;

    f32x4 acc[4][4] = {};

    const int r15 = lane & 15;
    const int khalf = (lane >> 4) << 3;
    const int xorv = (r15 & 7) << 3;

    const int srow = t >> 3;                        // 0..31
    const int scol = (((t & 7) ^ (srow & 7)) << 3); // pre-swizzled global column
    const u16* Ag = A + (size_t)(m0 + srow) * K + scol;
    const u16* Bg = BT + (size_t)(n0 + srow) * K + scol;

    const int nt = K / BK;

#define ISSUE(buf_, tile_)                                                           \
    {                                                                                \
        u16* dst_ = smem + (buf_) * BUFE;                                            \
        const int kt_ = (tile_) * BK;                                                \
        _Pragma("unroll")                                                            \
        for (int i = 0; i < 4; ++i)                                                  \
            gload_lds16(Ag + (size_t)(i * 32) * K + kt_, &dst_[i * 2048 + t * 8]);   \
        _Pragma("unroll")                                                            \
        for (int i = 0; i < 4; ++i)                                                  \
            gload_lds16(Bg + (size_t)(i * 32) * K + kt_, &dst_[8192 + i * 2048 + t * 8]); \
    }

    ISSUE(0, 0);
    ISSUE(1, 1);

    for (int tt = 0; tt < nt; ++tt) {
        const int d = tt & 1;

        if (tt + 1 < nt) WAITVM8(); else WAITVM0();
        BARRIER();
        SCHEDBAR();

        const u16* As = smem + d * BUFE;
        const u16* Bs = As + BM * BK;
        bf16x8 af[4][2], bf[4][2];
#pragma unroll
        for (int mi = 0; mi < 4; ++mi)
#pragma unroll
            for (int kk = 0; kk < 2; ++kk)
                af[mi][kk] = *(const bf16x8*)&As[(wr * 64 + mi * 16 + r15) * BK + ((kk * 32 + khalf) ^ xorv)];
#pragma unroll
        for (int ni = 0; ni < 4; ++ni)
#pragma unroll
            for (int kk = 0; kk < 2; ++kk)
                bf[ni][kk] = *(const bf16x8*)&Bs[(wc * 64 + ni * 16 + r15) * BK + ((kk * 32 + khalf) ^ xorv)];
#pragma unroll
        for (int kk = 0; kk < 2; ++kk)
#pragma unroll
            for (int mi = 0; mi < 4; ++mi)
#pragma unroll
                for (int ni = 0; ni < 4; ++ni)
                    acc[mi][ni] = __builtin_amdgcn_mfma_f32_16x16x32_bf16(af[mi][kk], bf[ni][kk], acc[mi][ni], 0, 0, 0);

        SCHEDBAR();
        BARRIER();
        if (tt + 2 < nt) ISSUE(d, tt + 2);
    }
#undef ISSUE

    // ---- coalesced epilogue: per-wave LDS staging (wave-private, 76-float pad) ----
    float* ep = (float*)smem + w * (16 * 76);
    const int lg = lane >> 4;
#pragma unroll
    for (int mi = 0; mi < 4; ++mi) {
#pragma unroll
        for (int ni = 0; ni < 4; ++ni)
#pragma unroll
            for (int j = 0; j < 4; ++j)
                ep[(lg * 4 + j) * 76 + ni * 16 + r15] = acc[mi][ni][j];
#pragma unroll
        for (int p = 0; p < 4; ++p) {
            int lr = p * 4 + lg;
            f32x4 v = *(f32x4*)&ep[lr * 76 + r15 * 4];
            int grow = m0 + wr * 64 + mi * 16 + lr;
            int gcol = n0 + wc * 64 + r15 * 4;
            float4 bv = *(const float4*)&bias[gcol];
            float o0 = v[0] + bv.x, o1 = v[1] + bv.y, o2 = v[2] + bv.z, o3 = v[3] + bv.w;
            if (EPI == EPI_GELU_BF16) {
                o0 = gelu_tanh(o0); o1 = gelu_tanh(o1); o2 = gelu_tanh(o2); o3 = gelu_tanh(o3);
            }
            if (EPI == EPI_RES_F32) {
                size_t off = (size_t)grow * N + gcol;
                float4 rv = *(const float4*)&res[off];
                float4 ov = make_float4(o0 + rv.x, o1 + rv.y, o2 + rv.z, o3 + rv.w);
                *(float4*)((float*)outp + off) = ov;
            } else {
                uint2 ov;
                ov.x = (u32)f2bf(o0) | ((u32)f2bf(o1) << 16);
                ov.y = (u32)f2bf(o2) | ((u32)f2bf(o3) << 16);
                *(uint2*)((u16*)outp + (size_t)grow * N + gcol) = ov;
            }
        }
    }
}

// ---------------- windowed attention v2: one block per (window, head-group of 4) ----------------
// 256 threads = 4 waves; wave w handles head g*4+w; lane = query row (49 active).
// K,V slices staged ONCE per block, bf16->fp32 unpacked cooperatively (no per-lane
// redundant unpack). All K/V reads are wave-uniform LDS broadcasts (conflict-free).
// Output accumulated in LDS (16B-chunk XOR swizzle) and written as full 256B
// row-segments -> no partial-line RMW write amplification.
__global__ __launch_bounds__(256) void attn_kernel(const u16* __restrict__ qkv, u16* __restrict__ aout) {
    __shared__ float Kf[49 * 128];   // 25088 B
    __shared__ float Vf[49 * 128];   // 25088 B
    __shared__ u16  Os[49 * 128];    // 12544 B   (62.7 KB total -> 2 blocks/CU)

    const int wdw = blockIdx.x;      // window
    const int g = blockIdx.y;        // head group (4 heads)
    const int t = threadIdx.x;
    const int lane = t & 63;
    const int w = t >> 6;
    const int b = wdw >> 6, wy = (wdw >> 3) & 7, wx = wdw & 7;
    const int base_row = b * 3136 + wy * 7 * 56 + wx * 7;

    // ---- stage K,V slice (cols [512+g*128,+128) and [1024+g*128,+128)) as fp32 ----
    for (int c = t; c < 1568; c += 256) {
        int kv = (c >= 784) ? 1 : 0;
        int cc = c - kv * 784;
        int r = cc >> 4, j = cc & 15;            // 16 chunks of 8 elems per row
        int gr = base_row + (r / 7) * 56 + (r % 7);
        uint4 v = *(const uint4*)(qkv + (size_t)gr * 1536 + 512 + kv * 512 + g * 128 + j * 8);
        float* dst = (kv ? Vf : Kf) + r * 128 + j * 8;
        float4 a, bq;
        a.x = __uint_as_float(v.x << 16); a.y = __uint_as_float(v.x & 0xffff0000u);
        a.z = __uint_as_float(v.y << 16); a.w = __uint_as_float(v.y & 0xffff0000u);
        bq.x = __uint_as_float(v.z << 16); bq.y = __uint_as_float(v.z & 0xffff0000u);
        bq.z = __uint_as_float(v.w << 16); bq.w = __uint_as_float(v.w & 0xffff0000u);
        ((float4*)dst)[0] = a;
        ((float4*)dst)[1] = bq;
    }
    __syncthreads();

    if (lane < 49) {
        const int hh = g * 4 + w;
        const int gr = base_row + (lane / 7) * 56 + (lane % 7);
        // Q row (64B) from global, unpack to fp32
        const u16* qp = qkv + (size_t)gr * 1536 + hh * 32;
        float q[32];
#pragma unroll
        for (int i = 0; i < 4; ++i) {
            uint4 v = *(const uint4*)(qp + i * 8);
            q[i * 8 + 0] = __uint_as_float(v.x << 16); q[i * 8 + 1] = __uint_as_float(v.x & 0xffff0000u);
            q[i * 8 + 2] = __uint_as_float(v.y << 16); q[i * 8 + 3] = __uint_as_float(v.y & 0xffff0000u);
            q[i * 8 + 4] = __uint_as_float(v.z << 16); q[i * 8 + 5] = __uint_as_float(v.z & 0xffff0000u);
            q[i * 8 + 6] = __uint_as_float(v.w << 16); q[i * 8 + 7] = __uint_as_float(v.w & 0xffff0000u);
        }
        // QK^T: K rows broadcast from LDS
        float s[49];
        float mx = -1e30f;
        const float* kbase = Kf + w * 32;
#pragma unroll 2
        for (int m = 0; m < 49; ++m) {
            const float4* kp = (const float4*)(kbase + m * 128);
            float acc = 0.f;
#pragma unroll
            for (int i = 0; i < 8; ++i) {
                float4 kv4 = kp[i];
                acc = fmaf(q[i * 4 + 0], kv4.x, acc);
                acc = fmaf(q[i * 4 + 1], kv4.y, acc);
                acc = fmaf(q[i * 4 + 2], kv4.z, acc);
                acc = fmaf(q[i * 4 + 3], kv4.w, acc);
            }
            acc *= SCALE_ATTN;
            s[m] = acc;
            mx = fmaxf(mx, acc);
        }
        float sum = 0.f;
#pragma unroll 2
        for (int m = 0; m < 49; ++m) { float e = __expf(s[m] - mx); s[m] = e; sum += e; }
        float inv = 1.f / sum;
        // PV: V rows broadcast from LDS
        float o[32];
#pragma unroll
        for (int d = 0; d < 32; ++d) o[d] = 0.f;
        const float* vbase = Vf + w * 32;
#pragma unroll 2
        for (int m = 0; m < 49; ++m) {
            float p = s[m] * inv;
            const float4* vp = (const float4*)(vbase + m * 128);
#pragma unroll
            for (int i = 0; i < 8; ++i) {
                float4 vv = vp[i];
                o[i * 4 + 0] = fmaf(p, vv.x, o[i * 4 + 0]);
                o[i * 4 + 1] = fmaf(p, vv.y, o[i * 4 + 1]);
                o[i * 4 + 2] = fmaf(p, vv.z, o[i * 4 + 2]);
                o[i * 4 + 3] = fmaf(p, vv.w, o[i * 4 + 3]);
            }
        }
        // store to Os with 16B-chunk XOR swizzle (row = lane)
#pragma unroll
        for (int j = 0; j < 4; ++j) {
            uint4 ov;
            ov.x = (u32)f2bf(o[j * 8 + 0]) | ((u32)f2bf(o[j * 8 + 1]) << 16);
            ov.y = (u32)f2bf(o[j * 8 + 2]) | ((u32)f2bf(o[j * 8 + 3]) << 16);
            ov.z = (u32)f2bf(o[j * 8 + 4]) | ((u32)f2bf(o[j * 8 + 5]) << 16);
            ov.w = (u32)f2bf(o[j * 8 + 6]) | ((u32)f2bf(o[j * 8 + 7]) << 16);
            int cj = (w * 4 + j) ^ (lane & 15);
            *(uint4*)(Os + lane * 128 + cj * 8) = ov;
        }
    }
    __syncthreads();

    // ---- cooperative coalesced writeout: full 256B row-segments ----
    for (int c = t; c < 784; c += 256) {
        int r = c >> 4, j = c & 15;
        int cj = j ^ (r & 15);
        uint4 v = *(const uint4*)(Os + r * 128 + cj * 8);
        int gr = base_row + (r / 7) * 56 + (r % 7);
        *(uint4*)(aout + (size_t)gr * 512 + g * 128 + j * 8) = v;
    }
}

// ---------------- launch ----------------
extern "C" void kernel_launch(void* const* d_in, const int* in_sizes, int n_in,
                              void* d_out, int out_size, void* d_ws, size_t ws_size,
                              hipStream_t stream) {
    (void)in_sizes; (void)n_in; (void)out_size; (void)ws_size;
    const float* x      = (const float*)d_in[0];
    const float* ln1_g  = (const float*)d_in[1];
    const float* ln1_b  = (const float*)d_in[2];
    const float* qkv_w  = (const float*)d_in[3];
    const float* qkv_b  = (const float*)d_in[4];
    const float* proj_w = (const float*)d_in[5];
    const float* proj_b = (const float*)d_in[6];
    const float* ln2_g  = (const float*)d_in[7];
    const float* ln2_b  = (const float*)d_in[8];
    const float* mlp_w1 = (const float*)d_in[9];
    const float* mlp_b1 = (const float*)d_in[10];
    const float* mlp_w2 = (const float*)d_in[11];
    const float* mlp_b2 = (const float*)d_in[12];
    float* out = (float*)d_out;

    const int M = MROWS;
    char* ws = (char*)d_ws;
    const size_t SZ_H   = (size_t)M * 512 * 2;
    const size_t SZ_X2  = (size_t)M * 512 * 4;
    const size_t SZ_BIG = (size_t)M * 2048 * 2;
    u16*   h    = (u16*)ws;
    float* x2   = (float*)(ws + SZ_H);
    u16*   big  = (u16*)(ws + SZ_H + SZ_X2);
    u16*   qkv_wT  = (u16*)(ws + SZ_H + SZ_X2 + SZ_BIG);
    u16*   proj_wT = qkv_wT + 1536 * 512;
    u16*   w1T     = proj_wT + 512 * 512;
    u16*   w2T     = w1T + 2048 * 512;

    transpose_cast<<<(512 * 1536 + 255) / 256, 256, 0, stream>>>(qkv_w, qkv_wT, 512, 1536);
    transpose_cast<<<(512 * 512 + 255) / 256, 256, 0, stream>>>(proj_w, proj_wT, 512, 512);
    transpose_cast<<<(512 * 2048 + 255) / 256, 256, 0, stream>>>(mlp_w1, w1T, 512, 2048);
    transpose_cast<<<(2048 * 512 + 255) / 256, 256, 0, stream>>>(mlp_w2, w2T, 2048, 512);

    ln_kernel<<<M / 4, 256, 0, stream>>>(x, ln1_g, ln1_b, h);

    gemm_bt<EPI_BF16><<<(M / BM) * (1536 / BN), 256, 0, stream>>>(h, qkv_wT, qkv_b, nullptr, big, M, 1536, 512, 1536 / BN);

    attn_kernel<<<dim3(2048, 4), 256, 0, stream>>>(big, h);

    gemm_bt<EPI_RES_F32><<<(M / BM) * (512 / BN), 256, 0, stream>>>(h, proj_wT, proj_b, x, x2, M, 512, 512, 512 / BN);

    ln_kernel<<<M / 4, 256, 0, stream>>>(x2, ln2_g, ln2_b, h);

    gemm_bt<EPI_GELU_BF16><<<(M / BM) * (2048 / BN), 256, 0, stream>>>(h, w1T, mlp_b1, nullptr, big, M, 2048, 512, 2048 / BN);

    gemm_bt<EPI_RES_F32><<<(M / BM) * (512 / BN), 256, 0, stream>>>(big, w2T, mlp_b2, x2, out, M, 512, 2048, 512 / BN);
}

// Round 9
// 1233.923 us; speedup vs baseline: 1.4558x; 1.4558x over previous
//
#include <hip/hip_runtime.h>
#include <hip/hip_bf16.h>
#include <math.h>

typedef unsigned short u16;
typedef unsigned int u32;
typedef __bf16 bf16x8 __attribute__((ext_vector_type(8)));
typedef float f32x4 __attribute__((ext_vector_type(4)));

#define MROWS 100352   // 32 * 56 * 56
#define CDIM 512
#define SCALE_ATTN 0.17677669529663687f

__device__ __forceinline__ u16 f2bf(float f) {
    u32 u = __float_as_uint(f);
    u32 r = (u + 0x7fffu + ((u >> 16) & 1u)) >> 16;   // RNE
    return (u16)r;
}

__device__ __forceinline__ u32 cvtpk_bf16(float lo, float hi) {
    u32 r;
    asm volatile("v_cvt_pk_bf16_f32 %0, %1, %2" : "=v"(r) : "v"(lo), "v"(hi));
    return r;
}

// ---------------- transpose + cast: fp32 W[K][N] -> bf16 WT[N][K] ----------------
__global__ void transpose_cast(const float* __restrict__ W, u16* __restrict__ WT, int K, int N) {
    int idx = blockIdx.x * 256 + threadIdx.x;
    if (idx >= K * N) return;
    int k = idx / N, n = idx % N;
    WT[(size_t)n * K + k] = f2bf(W[idx]);
}

// ---------------- LayerNorm fp32 -> bf16, one wave per row (C=512) ----------------
__global__ __launch_bounds__(256) void ln_kernel(const float* __restrict__ x, const float* __restrict__ g,
                                                 const float* __restrict__ bta, u16* __restrict__ out) {
    int row = blockIdx.x * 4 + (threadIdx.x >> 6);
    int lane = threadIdx.x & 63;
    const float* xr = x + (size_t)row * CDIM + lane * 8;
    float4 v0 = *(const float4*)xr;
    float4 v1 = *(const float4*)(xr + 4);
    float xv[8] = {v0.x, v0.y, v0.z, v0.w, v1.x, v1.y, v1.z, v1.w};
    float s = 0.f, ss = 0.f;
#pragma unroll
    for (int i = 0; i < 8; ++i) { s += xv[i]; ss += xv[i] * xv[i]; }
#pragma unroll
    for (int o = 1; o < 64; o <<= 1) { s += __shfl_xor(s, o); ss += __shfl_xor(ss, o); }
    float mu = s * (1.f / CDIM);
    float var = ss * (1.f / CDIM) - mu * mu;
    float rs = rsqrtf(var + 1e-6f);
    int c = lane * 8;
    u32 pk[4];
#pragma unroll
    for (int i = 0; i < 4; ++i) {
        float y0 = (xv[2 * i] - mu) * rs * g[c + 2 * i] + bta[c + 2 * i];
        float y1 = (xv[2 * i + 1] - mu) * rs * g[c + 2 * i + 1] + bta[c + 2 * i + 1];
        pk[i] = (u32)f2bf(y0) | ((u32)f2bf(y1) << 16);
    }
    uint4 ov; ov.x = pk[0]; ov.y = pk[1]; ov.z = pk[2]; ov.w = pk[3];
    *(uint4*)(out + (size_t)row * CDIM + c) = ov;
}

// ---------------- bf16 GEMM: C[M,N] = A[M,K] * BT[N,K]^T (r7 structure, unchanged) ----------------
#define BM 128
#define BN 128
#define BK 64
#define BUFE (BM * BK + BN * BK)   // 16384 u16 = 32KB per buffer

enum { EPI_BF16 = 0, EPI_GELU_BF16 = 1, EPI_RES_F32 = 2 };

__device__ __forceinline__ void gload_lds16(const void* g, void* l) {
    __builtin_amdgcn_global_load_lds(
        (const __attribute__((address_space(1))) u32*)g,
        (__attribute__((address_space(3))) u32*)l, 16, 0, 0);
}

#define WAITVM8() asm volatile("s_waitcnt vmcnt(8)" ::: "memory")
#define WAITVM12() asm volatile("s_waitcnt vmcnt(12)" ::: "memory")
#define WAITVM0() asm volatile("s_waitcnt vmcnt(0)" ::: "memory")
#define BARRIER() __builtin_amdgcn_s_barrier()
#define SCHEDBAR() __builtin_amdgcn_sched_barrier(0)

__device__ __forceinline__ float gelu_tanh(float x) {
    float y = 0.7978845608028654f * (x + 0.044715f * x * x * x);
    y = fmaxf(y, -20.f);
    float u = __expf(-2.f * y);
    float th = (1.f - u) / (1.f + u);
    return 0.5f * x * (1.f + th);
}

template <int EPI>
__global__ __launch_bounds__(256, 2) void gemm_bt(const u16* __restrict__ A, const u16* __restrict__ BT,
                                                  const float* __restrict__ bias, const float* __restrict__ res,
                                                  void* __restrict__ outp, int M, int N, int K, int nnb) {
    __shared__ __align__(16) u16 smem[2 * BUFE];   // 64 KB

    const int t = threadIdx.x;
    const int lane = t & 63;
    const int w = t >> 6;
    const int wr = w >> 1, wc = w & 1;

    const int nwg = gridDim.x;
    const int chunk = nwg >> 3;
    const int wg = (blockIdx.x & 7) * chunk + (blockIdx.x >> 3);
    const int m0 = (wg / nnb) * BM;
    const int n0 = (wg % nnb) * BN;

    f32x4 acc[4][4] = {};

    const int r15 = lane & 15;
    const int khalf = (lane >> 4) << 3;
    const int xorv = (r15 & 7) << 3;

    const int srow = t >> 3;
    const int scol = (((t & 7) ^ (srow & 7)) << 3);
    const u16* Ag = A + (size_t)(m0 + srow) * K + scol;
    const u16* Bg = BT + (size_t)(n0 + srow) * K + scol;

    const int nt = K / BK;

#define ISSUE(buf_, tile_)                                                           \
    {                                                                                \
        u16* dst_ = smem + (buf_) * BUFE;                                            \
        const int kt_ = (tile_) * BK;                                                \
        _Pragma("unroll")                                                            \
        for (int i = 0; i < 4; ++i)                                                  \
            gload_lds16(Ag + (size_t)(i * 32) * K + kt_, &dst_[i * 2048 + t * 8]);   \
        _Pragma("unroll")                                                            \
        for (int i = 0; i < 4; ++i)                                                  \
            gload_lds16(Bg + (size_t)(i * 32) * K + kt_, &dst_[8192 + i * 2048 + t * 8]); \
    }

    ISSUE(0, 0);
    ISSUE(1, 1);

    for (int tt = 0; tt < nt; ++tt) {
        const int d = tt & 1;

        if (tt + 1 < nt) WAITVM8(); else WAITVM0();
        BARRIER();
        SCHEDBAR();

        const u16* As = smem + d * BUFE;
        const u16* Bs = As + BM * BK;
        bf16x8 af[4][2], bf[4][2];
#pragma unroll
        for (int mi = 0; mi < 4; ++mi)
#pragma unroll
            for (int kk = 0; kk < 2; ++kk)
                af[mi][kk] = *(const bf16x8*)&As[(wr * 64 + mi * 16 + r15) * BK + ((kk * 32 + khalf) ^ xorv)];
#pragma unroll
        for (int ni = 0; ni < 4; ++ni)
#pragma unroll
            for (int kk = 0; kk < 2; ++kk)
                bf[ni][kk] = *(const bf16x8*)&Bs[(wc * 64 + ni * 16 + r15) * BK + ((kk * 32 + khalf) ^ xorv)];
#pragma unroll
        for (int kk = 0; kk < 2; ++kk)
#pragma unroll
            for (int mi = 0; mi < 4; ++mi)
#pragma unroll
                for (int ni = 0; ni < 4; ++ni)
                    acc[mi][ni] = __builtin_amdgcn_mfma_f32_16x16x32_bf16(af[mi][kk], bf[ni][kk], acc[mi][ni], 0, 0, 0);

        SCHEDBAR();
        BARRIER();
        if (tt + 2 < nt) ISSUE(d, tt + 2);
    }
#undef ISSUE

    float* ep = (float*)smem + w * (16 * 76);
    const int lg = lane >> 4;
#pragma unroll
    for (int mi = 0; mi < 4; ++mi) {
#pragma unroll
        for (int ni = 0; ni < 4; ++ni)
#pragma unroll
            for (int j = 0; j < 4; ++j)
                ep[(lg * 4 + j) * 76 + ni * 16 + r15] = acc[mi][ni][j];
#pragma unroll
        for (int p = 0; p < 4; ++p) {
            int lr = p * 4 + lg;
            f32x4 v = *(f32x4*)&ep[lr * 76 + r15 * 4];
            int grow = m0 + wr * 64 + mi * 16 + lr;
            int gcol = n0 + wc * 64 + r15 * 4;
            float4 bv = *(const float4*)&bias[gcol];
            float o0 = v[0] + bv.x, o1 = v[1] + bv.y, o2 = v[2] + bv.z, o3 = v[3] + bv.w;
            if (EPI == EPI_GELU_BF16) {
                o0 = gelu_tanh(o0); o1 = gelu_tanh(o1); o2 = gelu_tanh(o2); o3 = gelu_tanh(o3);
            }
            if (EPI == EPI_RES_F32) {
                size_t off = (size_t)grow * N + gcol;
                float4 rv = *(const float4*)&res[off];
                float4 ov = make_float4(o0 + rv.x, o1 + rv.y, o2 + rv.z, o3 + rv.w);
                *(float4*)((float*)outp + off) = ov;
            } else {
                uint2 ov;
                ov.x = (u32)f2bf(o0) | ((u32)f2bf(o1) << 16);
                ov.y = (u32)f2bf(o2) | ((u32)f2bf(o3) << 16);
                *(uint2*)((u16*)outp + (size_t)grow * N + gcol) = ov;
            }
        }
    }
}

// ---------------- windowed attention v3: MFMA, one block per window ----------------
// 4 waves; wave w processes heads w*4+r for rounds r=0..3.
// Per round (wave-private, no barriers): stage Q,K (global_load_lds, chunk-XOR via
// pre-swizzled source), V reg-staged transposed into Vt[d][k] (lane-owns-bank b32
// writes). S^T = K*Q^T (swapped: softmax over k = 16 in-lane regs + shfl 16/32).
// P -> bf16 (cvt_pk) into dead Q buffer, O = P*V. O into block-shared Os[64][512]
// (chunk-XOR by q), final cooperative full-row writeout.
// Counted vmcnt(12): next round's 12 VMEM ops issued before this round's wait.
__global__ __launch_bounds__(256) void attn_kernel(const u16* __restrict__ qkv, u16* __restrict__ aout) {
    __shared__ __align__(16) u16 smem[73728];   // 144 KB: Os[64][512]=32768 elems + 4 x 10240 wave region

    const int t = threadIdx.x;
    const int lane = t & 63;
    const int w = t >> 6;
    const int g = lane >> 4;
    const int r15 = lane & 15;
    const int wdw = blockIdx.x;
    const int b = wdw >> 6, wy = (wdw >> 3) & 7, wx = wdw & 7;
    const int base_row = b * 3136 + wy * 7 * 56 + wx * 7;

    const int WB = 32768 + w * 10240;   // wave region base (elems)
    // Qb[bb]: WB + bb*2048 ; Kb[bb]: WB + 4096 + bb*2048 ; Vt: WB + 8192

    // --- per-lane staging constants (round-invariant) ---
    const int sg_row = lane >> 2;                 // 0..15
    const int sg_c = (lane & 3) ^ (sg_row & 3);   // logical d-chunk for Q/K staging
    int grq[4];
#pragma unroll
    for (int u = 0; u < 4; ++u) {
        int rr = u * 16 + sg_row; rr = rr > 48 ? 48 : rr;
        grq[u] = base_row + (rr / 7) * 56 + rr % 7;
    }
    const int r2v = lane & 31;                    // k-pair index for V staging
    const int dh = lane >> 5;                     // d-half (0: d 0-15, 1: d 16-31)
    int k0 = 2 * r2v, k1 = 2 * r2v + 1;
    k0 = k0 > 48 ? 48 : k0; k1 = k1 > 48 ? 48 : k1;
    const int grv0 = base_row + (k0 / 7) * 56 + k0 % 7;
    const int grv1 = base_row + (k1 / 7) * 56 + k1 % 7;

    const int fragsw = ((g ^ (r15 & 3)) << 3);    // frag-read chunk offset for [64][32] bufs

#define ATISSUE(rr_, bb_, va0_, va1_, vb0_, vb1_)                                    \
    {                                                                                \
        const int hh_ = w * 4 + (rr_);                                               \
        _Pragma("unroll")                                                            \
        for (int u = 0; u < 4; ++u)                                                  \
            gload_lds16(qkv + (size_t)grq[u] * 1536 + hh_ * 32 + sg_c * 8,           \
                        &smem[WB + (bb_) * 2048 + u * 512 + lane * 8]);              \
        _Pragma("unroll")                                                            \
        for (int u = 0; u < 4; ++u)                                                  \
            gload_lds16(qkv + (size_t)grq[u] * 1536 + 512 + hh_ * 32 + sg_c * 8,     \
                        &smem[WB + 4096 + (bb_) * 2048 + u * 512 + lane * 8]);       \
        const u16* vs0_ = qkv + (size_t)grv0 * 1536 + 1024 + hh_ * 32 + dh * 16;     \
        const u16* vs1_ = qkv + (size_t)grv1 * 1536 + 1024 + hh_ * 32 + dh * 16;     \
        va0_ = *(const uint4*)vs0_; va1_ = *(const uint4*)(vs0_ + 8);                \
        vb0_ = *(const uint4*)vs1_; vb1_ = *(const uint4*)(vs1_ + 8);                \
    }

    uint4 va0[2], va1[2], vb0[2], vb1[2];
    ATISSUE(0, 0, va0[0], va1[0], vb0[0], vb1[0]);

#pragma unroll
    for (int r = 0; r < 4; ++r) {
        const int bb = r & 1;
        const int hh = w * 4 + r;
        if (r < 3) ATISSUE(r + 1, bb ^ 1, va0[(r + 1) & 1], va1[(r + 1) & 1], vb0[(r + 1) & 1], vb1[(r + 1) & 1]);
        if (r < 3) WAITVM12(); else WAITVM0();
        SCHEDBAR();

        // ---- pack V^T into Vt[d 0..31][k 0..63] (chunk-XOR by d&7) ----
        {
            u32 A[8], B[8];
            A[0] = va0[bb].x; A[1] = va0[bb].y; A[2] = va0[bb].z; A[3] = va0[bb].w;
            A[4] = va1[bb].x; A[5] = va1[bb].y; A[6] = va1[bb].z; A[7] = va1[bb].w;
            B[0] = vb0[bb].x; B[1] = vb0[bb].y; B[2] = vb0[bb].z; B[3] = vb0[bb].w;
            B[4] = vb1[bb].x; B[5] = vb1[bb].y; B[6] = vb1[bb].z; B[7] = vb1[bb].w;
#pragma unroll
            for (int i = 0; i < 16; ++i) {
                u32 a16 = (A[i >> 1] >> (16 * (i & 1))) & 0xffffu;
                u32 b16 = (B[i >> 1] >> (16 * (i & 1))) & 0xffffu;
                u32 val = a16 | (b16 << 16);
                int d = dh * 16 + i;
                int cph = (r2v >> 2) ^ (d & 7);
                ((u32*)smem)[(WB + 8192 + d * 64 + cph * 8 + 2 * (r2v & 3)) >> 1] = val;
            }
        }

        // ---- S^T = K * Q^T : 16 MFMA ----
        const int QB = WB + bb * 2048;
        const int KB = WB + 4096 + bb * 2048;
        f32x4 s[4][4] = {};
        {
            bf16x8 kf[4], qf[4];
#pragma unroll
            for (int mi = 0; mi < 4; ++mi)
                kf[mi] = *(const bf16x8*)&smem[KB + (16 * mi + r15) * 32 + fragsw];
#pragma unroll
            for (int ni = 0; ni < 4; ++ni)
                qf[ni] = *(const bf16x8*)&smem[QB + (16 * ni + r15) * 32 + fragsw];
#pragma unroll
            for (int mi = 0; mi < 4; ++mi)
#pragma unroll
                for (int ni = 0; ni < 4; ++ni)
                    s[mi][ni] = __builtin_amdgcn_mfma_f32_16x16x32_bf16(kf[mi], qf[ni], s[mi][ni], 0, 0, 0);
        }

        // ---- softmax over k (rows of S^T): in-lane 16 regs + shfl 16/32, per ni ----
        float inv4[4];
#pragma unroll
        for (int ni = 0; ni < 4; ++ni) {
            float mx = -1e30f;
#pragma unroll
            for (int mi = 0; mi < 4; ++mi)
#pragma unroll
                for (int jj = 0; jj < 4; ++jj) {
                    float v = s[mi][ni][jj] * SCALE_ATTN;
                    if (mi == 3 && !(g == 0 && jj == 0)) v = -1e30f;   // k >= 49 pad
                    s[mi][ni][jj] = v;
                    mx = fmaxf(mx, v);
                }
            mx = fmaxf(mx, __shfl_xor(mx, 16));
            mx = fmaxf(mx, __shfl_xor(mx, 32));
            float sum = 0.f;
#pragma unroll
            for (int mi = 0; mi < 4; ++mi)
#pragma unroll
                for (int jj = 0; jj < 4; ++jj) {
                    float e = __expf(s[mi][ni][jj] - mx);
                    s[mi][ni][jj] = e;
                    sum += e;
                }
            sum += __shfl_xor(sum, 16);
            sum += __shfl_xor(sum, 32);
            inv4[ni] = 1.f / sum;
        }

        // ---- PV in two k-halves: P(bf16) -> Qb (dead), O = P*V ----
        f32x4 o[4][2] = {};
#pragma unroll
        for (int kh = 0; kh < 2; ++kh) {
            // write P half: P[q 0..63][kl 0..31], chunk-XOR by q&3
#pragma unroll
            for (int m1 = 0; m1 < 2; ++m1) {
                const int mi = 2 * kh + m1;
#pragma unroll
                for (int ni = 0; ni < 4; ++ni)
#pragma unroll
                    for (int jp = 0; jp < 2; ++jp) {
                        float p0 = s[mi][ni][2 * jp] * inv4[ni];
                        float p1 = s[mi][ni][2 * jp + 1] * inv4[ni];
                        u32 val = cvtpk_bf16(p0, p1);
                        int q = 16 * ni + r15;
                        int cph = (2 * m1 + (g >> 1)) ^ (r15 & 3);
                        int off = 4 * (g & 1) + 2 * jp;
                        ((u32*)smem)[(QB + q * 32 + cph * 8 + off) >> 1] = val;
                    }
            }
            // PV MFMAs for this half
            bf16x8 pf[4], vf[2];
#pragma unroll
            for (int mi = 0; mi < 4; ++mi)
                pf[mi] = *(const bf16x8*)&smem[QB + (16 * mi + r15) * 32 + fragsw];
#pragma unroll
            for (int ni = 0; ni < 2; ++ni)
                vf[ni] = *(const bf16x8*)&smem[WB + 8192 + (16 * ni + r15) * 64 + ((((4 * kh + g) ^ (r15 & 7))) << 3)];
#pragma unroll
            for (int mi = 0; mi < 4; ++mi)
#pragma unroll
                for (int ni = 0; ni < 2; ++ni)
                    o[mi][ni] = __builtin_amdgcn_mfma_f32_16x16x32_bf16(pf[mi], vf[ni], o[mi][ni], 0, 0, 0);
        }

        // ---- O -> Os[64][512] (chunk-XOR by (q>>2)&7), pair-packed b32 writes ----
#pragma unroll
        for (int mi = 0; mi < 4; ++mi)
#pragma unroll
            for (int ni = 0; ni < 2; ++ni)
#pragma unroll
                for (int jj = 0; jj < 4; ++jj) {
                    float ov = o[mi][ni][jj];
                    float op = __shfl_xor(ov, 1);
                    int q = 16 * mi + 4 * g + jj;
                    bool valid = (mi < 3) || (g == 0 && jj == 0);   // q < 49
                    if (((lane & 1) == 0) && valid) {
                        int col = hh * 32 + 16 * ni + r15;          // even
                        int chv = ((col >> 3) ^ ((q >> 2) & 7));
                        ((u32*)smem)[(q * 512 + chv * 8 + (col & 7)) >> 1] = cvtpk_bf16(ov, op);
                    }
                }
    }
#undef ATISSUE

    __syncthreads();
    // ---- cooperative writeout: full 1KB rows ----
    for (int c = t; c < 3136; c += 256) {
        int r = c >> 6, j = c & 63;
        int chv = j ^ ((r >> 2) & 7);
        uint4 v = *(const uint4*)&smem[r * 512 + chv * 8];
        int gr = base_row + (r / 7) * 56 + r % 7;
        *(uint4*)(aout + (size_t)gr * 512 + j * 8) = v;
    }
}

// ---------------- launch ----------------
extern "C" void kernel_launch(void* const* d_in, const int* in_sizes, int n_in,
                              void* d_out, int out_size, void* d_ws, size_t ws_size,
                              hipStream_t stream) {
    (void)in_sizes; (void)n_in; (void)out_size; (void)ws_size;
    const float* x      = (const float*)d_in[0];
    const float* ln1_g  = (const float*)d_in[1];
    const float* ln1_b  = (const float*)d_in[2];
    const float* qkv_w  = (const float*)d_in[3];
    const float* qkv_b  = (const float*)d_in[4];
    const float* proj_w = (const float*)d_in[5];
    const float* proj_b = (const float*)d_in[6];
    const float* ln2_g  = (const float*)d_in[7];
    const float* ln2_b  = (const float*)d_in[8];
    const float* mlp_w1 = (const float*)d_in[9];
    const float* mlp_b1 = (const float*)d_in[10];
    const float* mlp_w2 = (const float*)d_in[11];
    const float* mlp_b2 = (const float*)d_in[12];
    float* out = (float*)d_out;

    const int M = MROWS;
    char* ws = (char*)d_ws;
    const size_t SZ_H   = (size_t)M * 512 * 2;
    const size_t SZ_X2  = (size_t)M * 512 * 4;
    const size_t SZ_BIG = (size_t)M * 2048 * 2;
    u16*   h    = (u16*)ws;
    float* x2   = (float*)(ws + SZ_H);
    u16*   big  = (u16*)(ws + SZ_H + SZ_X2);
    u16*   qkv_wT  = (u16*)(ws + SZ_H + SZ_X2 + SZ_BIG);
    u16*   proj_wT = qkv_wT + 1536 * 512;
    u16*   w1T     = proj_wT + 512 * 512;
    u16*   w2T     = w1T + 2048 * 512;

    transpose_cast<<<(512 * 1536 + 255) / 256, 256, 0, stream>>>(qkv_w, qkv_wT, 512, 1536);
    transpose_cast<<<(512 * 512 + 255) / 256, 256, 0, stream>>>(proj_w, proj_wT, 512, 512);
    transpose_cast<<<(512 * 2048 + 255) / 256, 256, 0, stream>>>(mlp_w1, w1T, 512, 2048);
    transpose_cast<<<(2048 * 512 + 255) / 256, 256, 0, stream>>>(mlp_w2, w2T, 2048, 512);

    ln_kernel<<<M / 4, 256, 0, stream>>>(x, ln1_g, ln1_b, h);

    gemm_bt<EPI_BF16><<<(M / BM) * (1536 / BN), 256, 0, stream>>>(h, qkv_wT, qkv_b, nullptr, big, M, 1536, 512, 1536 / BN);

    attn_kernel<<<2048, 256, 0, stream>>>(big, h);

    gemm_bt<EPI_RES_F32><<<(M / BM) * (512 / BN), 256, 0, stream>>>(h, proj_wT, proj_b, x, x2, M, 512, 512, 512 / BN);

    ln_kernel<<<M / 4, 256, 0, stream>>>(x2, ln2_g, ln2_b, h);

    gemm_bt<EPI_GELU_BF16><<<(M / BM) * (2048 / BN), 256, 0, stream>>>(h, w1T, mlp_b1, nullptr, big, M, 2048, 512, 2048 / BN);

    gemm_bt<EPI_RES_F32><<<(M / BM) * (512 / BN), 256, 0, stream>>>(big, w2T, mlp_b2, x2, out, M, 512, 2048, 512 / BN);
}